// Round 3
// baseline (757.721 us; speedup 1.0000x reference)
//
#include <hip/hip_runtime.h>
#include <hip/hip_fp16.h>

#define B_ 2048
#define T_ 512
#define I_ 58   // input features
#define H_ 23   // hidden
#define G_ 69   // 3*H gates
#define TT_ 128 // t-tile per k_xproj block

// Constant-address-space pointer: forces wave-uniform W/b loads onto the
// scalar path (s_load + K$) instead of per-lane VMEM/LDS traffic.
typedef const __attribute__((address_space(4))) float* cfp4;
__device__ __forceinline__ cfp4 as_const(const float* p) {
    return (cfp4)(unsigned long long)p;
}

// Opaque register pin: the compiler cannot rematerialize (re-load) a value
// that an asm block may have produced/modified, so it MUST stay in a VGPR.
// Round-2 evidence: VGPR_Count=44 < 46 weights => weights were re-loaded
// from global every step (~46 latency-exposed L1 hits per step = the
// unexplained ~1350 cyc/step). This is the fix for that.
#define PIN(x) asm volatile("" : "+v"(x))

__device__ __forceinline__ float fast_rcp(float x) { return __builtin_amdgcn_rcpf(x); }
__device__ __forceinline__ float sigm(float x) { return fast_rcp(1.f + __expf(-x)); }
__device__ __forceinline__ float tanh_f(float x) {
    float e = __expf(-2.f * x);
    return (1.f - e) * fast_rcp(1.f + e);
}

// Kernel 1: x_proj -> xg[b][g][t] fp16 (transposed for the scan kernel).
// (unchanged — not the top dispatch; one change at a time)
__global__ __launch_bounds__(128, 2) void k_xproj(
    const float* __restrict__ x, const float* __restrict__ Wih,
    const float* __restrict__ bih, __half* __restrict__ xg)
{
    __shared__ float xs[TT_ * I_];          // 29696 B; reused as fp16 out-stage
    __half* os = (__half*)xs;               // union; G_*TT_*2 = 17664 B fits

    int tid = threadIdx.x;
    int b = blockIdx.x >> 2;                // T_/TT_ = 4 tiles per b
    int t0 = (blockIdx.x & 3) * TT_;

    // coalesced stage: tile = TT_*I_*4 B = 3712 float2 -> 29 per thread
    const float2* src = (const float2*)(x + ((size_t)b * T_ + t0) * I_);
    float2* xs2 = (float2*)xs;
#pragma unroll
    for (int i = 0; i < 29; ++i) xs2[i * TT_ + tid] = src[i * TT_ + tid];
    __syncthreads();

    // own column -> VGPRs (row stride 58 floats: 2-way bank alias = free)
    float xv[I_];
    const float* col = xs + tid * I_;
#pragma unroll
    for (int k = 0; k < I_; ++k) xv[k] = col[k];
    __syncthreads();   // everyone done reading xs before os overwrites it

    cfp4 W4 = as_const(Wih);
    cfp4 b4 = as_const(bih);
#pragma unroll 3
    for (int g = 0; g < G_; ++g) {
        float a0 = b4[g], a1 = 0.f, a2 = 0.f, a3 = 0.f;
        cfp4 wr = W4 + g * I_;
#pragma unroll
        for (int k = 0; k < 56; k += 4) {
            a0 = fmaf(wr[k + 0], xv[k + 0], a0);
            a1 = fmaf(wr[k + 1], xv[k + 1], a1);
            a2 = fmaf(wr[k + 2], xv[k + 2], a2);
            a3 = fmaf(wr[k + 3], xv[k + 3], a3);
        }
        a0 = fmaf(wr[56], xv[56], a0);
        a1 = fmaf(wr[57], xv[57], a1);
        os[g * TT_ + tid] = __float2half((a0 + a2) + (a1 + a3));
    }
    __syncthreads();

    // transposed write-out: per gate 128 halves = 256 B = 32 int2 chunks
    const int2* s2 = (const int2*)os;
#pragma unroll 1
    for (int idx = tid; idx < G_ * (TT_ / 4); idx += 128) {
        int g = idx >> 5;
        int c = idx & 31;
        __half* dst = xg + ((size_t)b * G_ + g) * T_ + t0;
        ((int2*)dst)[c] = s2[idx];
    }
}

// Kernel 2: GRU scan, ONE batch row per wave (grid = B waves = 2 waves/SIMD).
// Identical structure to round 2 (harness-verified correct), with ONE change:
// weights/biases are PINNED into VGPRs so they cannot be rematerialized as
// per-step global loads.
//
// Lane layout (per wave, one row b):
//   lanes 0..22   hold W_hh rows of the r-gate  (rowA = j)
//   lanes 32..54  hold W_hh rows of the z-gate  (rowA = H+j)
//   -> ONE 23-FMA pass computes both r and z dots.
//   n-gate dot computed redundantly in both halves (23 FMA).
//   h broadcast via v_readlane -> SGPR feeding v_fma directly (no LDS pipe).
//   One __shfl pulls z down to the lower half (overlaps the tanh).
//   Upper-half h evolves with wrong r but is NEVER read and stays bounded.
__global__ __launch_bounds__(64, 2) void k_scan(
    const __half* __restrict__ xg, const float* __restrict__ Whh,
    const float* __restrict__ bhh, const float* __restrict__ pw,
    const float* __restrict__ pb, float* __restrict__ out)
{
    const int lane = threadIdx.x;
    const int j = lane & 31;
    const bool up = lane >= 32;
    const bool act = lane < H_;          // only lanes 0..22 store
    const int jj = (j < H_) ? j : 0;     // clamp idle lanes to valid rows
    const int b = blockIdx.x;

    const int rowA = up ? (jj + H_) : jj;   // r-row (lower) / z-row (upper)
    const int rowN = jj + 2 * H_;           // n-row (both halves)

    float wA[H_], wN[H_];
#pragma unroll
    for (int k = 0; k < H_; ++k) {
        wA[k] = Whh[rowA * H_ + k];
        wN[k] = Whh[rowN * H_ + k];
    }
    float bA = bhh[rowA];
    float bN = bhh[rowN];
    float pwj = pw[jj], pbj = pb[jj];

    // Force all loop-invariant operands to be VGPR-resident for the whole
    // scan. Without this the compiler re-loads them inside the step loop.
#pragma unroll
    for (int k = 0; k < H_; ++k) { PIN(wA[k]); PIN(wN[k]); }
    PIN(bA); PIN(bN); PIN(pwj); PIN(pbj);

    // per-lane gate rows of xg: lower reads xr_j, upper reads xz_j; both read xn_j
    const int4* pA = (const int4*)(xg + ((size_t)b * G_ + rowA) * T_);
    const int4* pN = (const int4*)(xg + ((size_t)b * G_ + rowN) * T_);

    float* arow = out + (size_t)b * T_ * H_ + jj;

    int4 cA = pA[0], cN = pN[0];
    float h = 0.f;

#pragma unroll 1
    for (int c = 0; c < T_ / 8; ++c) {
        int4 nxA = {0, 0, 0, 0}, nxN = {0, 0, 0, 0};
        if (c + 1 < T_ / 8) {            // prefetch next 8-step chunk
            nxA = pA[c + 1];
            nxN = pN[c + 1];
        }
        const __half* hA = (const __half*)&cA;
        const __half* hN = (const __half*)&cN;
        float* ap = arow + (size_t)c * 8 * H_;
#pragma unroll
        for (int s = 0; s < 8; ++s) {
            // h broadcast: v_readlane -> SGPR (lanes 0..22 hold the true h),
            // interleaved with the dual dot (accA = r-dot | z-dot per half).
            float accA = bA, accN = bN;
#define KSTEP(k)                                                               \
            {                                                                  \
                float hk = __int_as_float(                                     \
                    __builtin_amdgcn_readlane(__float_as_int(h), k));          \
                accA = fmaf(wA[k], hk, accA);                                  \
                accN = fmaf(wN[k], hk, accN);                                  \
            }
            KSTEP(0)  KSTEP(1)  KSTEP(2)  KSTEP(3)  KSTEP(4)  KSTEP(5)
            KSTEP(6)  KSTEP(7)  KSTEP(8)  KSTEP(9)  KSTEP(10) KSTEP(11)
            KSTEP(12) KSTEP(13) KSTEP(14) KSTEP(15) KSTEP(16) KSTEP(17)
            KSTEP(18) KSTEP(19) KSTEP(20) KSTEP(21) KSTEP(22)
#undef KSTEP

            float xA = __half2float(hA[s]);  // xr (lower) / xz (upper)
            float xN = __half2float(hN[s]);  // xn (both halves)

            // one sigmoid pass activates r (lower half) AND z (upper half)
            float rz = sigm(xA + accA);

            // lower half: r is lane-local; pull z from the matching upper lane.
            // (shuffle latency overlaps the tanh below)
            float r = rz;
            float z = __shfl(rz, 32 + j, 64);

            float n = tanh_f(fmaf(r, accN, xN));
            h = fmaf(z, h - n, n);           // (1-z)*n + z*h
            if (act) ap[s * H_] = fmaf(pwj, h, pbj);
        }
        cA = nxA;
        cN = nxN;
    }
    if (act) out[(size_t)B_ * T_ * H_ + (size_t)b * H_ + jj] = h;
}

extern "C" void kernel_launch(void* const* d_in, const int* in_sizes, int n_in,
                              void* d_out, int out_size, void* d_ws, size_t ws_size,
                              hipStream_t stream) {
    const float* task = (const float*)d_in[0];  // (B, T, I)
    const float* Wih  = (const float*)d_in[1];  // (3H, I)
    const float* Whh  = (const float*)d_in[2];  // (3H, H)
    const float* bih  = (const float*)d_in[3];  // (3H,)
    const float* bhh  = (const float*)d_in[4];  // (3H,)
    const float* pw   = (const float*)d_in[5];  // (H,)
    const float* pb   = (const float*)d_in[6];  // (H,)
    float* out = (float*)d_out;                 // action_pred (B,T,H) ++ hidden (1,B,H)
    __half* xgbuf = (__half*)d_ws;              // transposed (B, G_, T) fp16 = 144.7 MB

    k_xproj<<<B_ * 4, TT_, 0, stream>>>(task, Wih, bih, xgbuf);
    k_scan<<<B_, 64, 0, stream>>>(xgbuf, Whh, bhh, pw, pb, out);
}

// Round 4
// 754.970 us; speedup vs baseline: 1.0036x; 1.0036x over previous
//
#include <hip/hip_runtime.h>
#include <hip/hip_fp16.h>

#define B_ 2048
#define T_ 512
#define I_ 58   // input features
#define H_ 23   // hidden
#define G_ 69   // 3*H gates
#define TT_ 128 // t-tile per k_xproj block

// Constant-address-space pointer: forces wave-uniform W/b loads onto the
// scalar path (s_load + K$) instead of per-lane VMEM/LDS traffic.
typedef const __attribute__((address_space(4))) float* cfp4;
__device__ __forceinline__ cfp4 as_const(const float* p) {
    return (cfp4)(unsigned long long)p;
}

// Opaque register pin (keeps a value live in a VGPR at this point; prevents
// rematerialization-by-reload). NOTE round-3 lesson: PIN alone does NOT stop
// the allocator from parking invariants in AGPRs — that is governed by the
// launch_bounds register budget, fixed below.
#define PIN(x) asm volatile("" : "+v"(x))

__device__ __forceinline__ float fast_rcp(float x) { return __builtin_amdgcn_rcpf(x); }
__device__ __forceinline__ float sigm(float x) { return fast_rcp(1.f + __expf(-x)); }
__device__ __forceinline__ float tanh_f(float x) {
    float e = __expf(-2.f * x);
    return (1.f - e) * fast_rcp(1.f + e);
}

// Kernel 1: x_proj -> xg[b][g][t] fp16 (transposed for the scan kernel).
// (unchanged — not the top dispatch; one change at a time)
__global__ __launch_bounds__(128, 2) void k_xproj(
    const float* __restrict__ x, const float* __restrict__ Wih,
    const float* __restrict__ bih, __half* __restrict__ xg)
{
    __shared__ float xs[TT_ * I_];          // 29696 B; reused as fp16 out-stage
    __half* os = (__half*)xs;               // union; G_*TT_*2 = 17664 B fits

    int tid = threadIdx.x;
    int b = blockIdx.x >> 2;                // T_/TT_ = 4 tiles per b
    int t0 = (blockIdx.x & 3) * TT_;

    // coalesced stage: tile = TT_*I_*4 B = 3712 float2 -> 29 per thread
    const float2* src = (const float2*)(x + ((size_t)b * T_ + t0) * I_);
    float2* xs2 = (float2*)xs;
#pragma unroll
    for (int i = 0; i < 29; ++i) xs2[i * TT_ + tid] = src[i * TT_ + tid];
    __syncthreads();

    // own column -> VGPRs (row stride 58 floats: 2-way bank alias = free)
    float xv[I_];
    const float* col = xs + tid * I_;
#pragma unroll
    for (int k = 0; k < I_; ++k) xv[k] = col[k];
    __syncthreads();   // everyone done reading xs before os overwrites it

    cfp4 W4 = as_const(Wih);
    cfp4 b4 = as_const(bih);
#pragma unroll 3
    for (int g = 0; g < G_; ++g) {
        float a0 = b4[g], a1 = 0.f, a2 = 0.f, a3 = 0.f;
        cfp4 wr = W4 + g * I_;
#pragma unroll
        for (int k = 0; k < 56; k += 4) {
            a0 = fmaf(wr[k + 0], xv[k + 0], a0);
            a1 = fmaf(wr[k + 1], xv[k + 1], a1);
            a2 = fmaf(wr[k + 2], xv[k + 2], a2);
            a3 = fmaf(wr[k + 3], xv[k + 3], a3);
        }
        a0 = fmaf(wr[56], xv[56], a0);
        a1 = fmaf(wr[57], xv[57], a1);
        os[g * TT_ + tid] = __float2half((a0 + a2) + (a1 + a3));
    }
    __syncthreads();

    // transposed write-out: per gate 128 halves = 256 B = 32 int2 chunks
    const int2* s2 = (const int2*)os;
#pragma unroll 1
    for (int idx = tid; idx < G_ * (TT_ / 4); idx += 128) {
        int g = idx >> 5;
        int c = idx & 31;
        __half* dst = xg + ((size_t)b * G_ + g) * T_ + t0;
        ((int2*)dst)[c] = s2[idx];
    }
}

// Kernel 2: GRU scan, ONE batch row per wave (grid = B waves = 2 waves/SIMD).
//
// ROUND-4 CHANGE (the only change): __launch_bounds__(64, 2) -> (64, 1).
// Evidence trail: VGPR_Count=44 < 46 live weights across rounds 2-3, with
// ~90 unexplained VALU insts/step (VALUBusy 55% of 1369cy/step = ~188
// insts/step vs ~91 hand-counted) => allocator parked the weights in AGPRs
// and shuttles them via v_accvgpr_read each use. The previous session hit
// the IDENTICAL pathology and fixed it with (64,1) — the min-waves=1 bound
// releases the full unified register budget so invariants stay arch-VGPR.
// Real occupancy is unaffected: kernel needs ~100-130 VGPR (>=2 waves/SIMD
// still fit) and the grid supplies exactly 2 waves/SIMD anyway.
//
// Lane layout (per wave, one row b):
//   lanes 0..22   hold W_hh rows of the r-gate  (rowA = j)
//   lanes 32..54  hold W_hh rows of the z-gate  (rowA = H+j)
//   -> ONE 23-FMA pass computes both r and z dots.
//   n-gate dot computed redundantly in both halves (23 FMA).
//   h broadcast via v_readlane -> SGPR feeding v_fma directly (no LDS pipe).
//   One __shfl pulls z down to the lower half (overlaps the tanh).
//   Upper-half h evolves with wrong r but is NEVER read and stays bounded.
__global__ __launch_bounds__(64, 1) void k_scan(
    const __half* __restrict__ xg, const float* __restrict__ Whh,
    const float* __restrict__ bhh, const float* __restrict__ pw,
    const float* __restrict__ pb, float* __restrict__ out)
{
    const int lane = threadIdx.x;
    const int j = lane & 31;
    const bool up = lane >= 32;
    const bool act = lane < H_;          // only lanes 0..22 store
    const int jj = (j < H_) ? j : 0;     // clamp idle lanes to valid rows
    const int b = blockIdx.x;

    const int rowA = up ? (jj + H_) : jj;   // r-row (lower) / z-row (upper)
    const int rowN = jj + 2 * H_;           // n-row (both halves)

    float wA[H_], wN[H_];
#pragma unroll
    for (int k = 0; k < H_; ++k) {
        wA[k] = Whh[rowA * H_ + k];
        wN[k] = Whh[rowN * H_ + k];
    }
    float bA = bhh[rowA];
    float bN = bhh[rowN];
    float pwj = pw[jj], pbj = pb[jj];

    // Keep all loop-invariant operands VGPR-resident for the whole scan.
#pragma unroll
    for (int k = 0; k < H_; ++k) { PIN(wA[k]); PIN(wN[k]); }
    PIN(bA); PIN(bN); PIN(pwj); PIN(pbj);

    // per-lane gate rows of xg: lower reads xr_j, upper reads xz_j; both read xn_j
    const int4* pA = (const int4*)(xg + ((size_t)b * G_ + rowA) * T_);
    const int4* pN = (const int4*)(xg + ((size_t)b * G_ + rowN) * T_);

    float* arow = out + (size_t)b * T_ * H_ + jj;

    int4 cA = pA[0], cN = pN[0];
    float h = 0.f;

#pragma unroll 1
    for (int c = 0; c < T_ / 8; ++c) {
        int4 nxA = {0, 0, 0, 0}, nxN = {0, 0, 0, 0};
        if (c + 1 < T_ / 8) {            // prefetch next 8-step chunk
            nxA = pA[c + 1];
            nxN = pN[c + 1];
        }
        const __half* hA = (const __half*)&cA;
        const __half* hN = (const __half*)&cN;
        float* ap = arow + (size_t)c * 8 * H_;
#pragma unroll
        for (int s = 0; s < 8; ++s) {
            // h broadcast: v_readlane -> SGPR (lanes 0..22 hold the true h),
            // interleaved with the dual dot (accA = r-dot | z-dot per half).
            float accA = bA, accN = bN;
#define KSTEP(k)                                                               \
            {                                                                  \
                float hk = __int_as_float(                                     \
                    __builtin_amdgcn_readlane(__float_as_int(h), k));          \
                accA = fmaf(wA[k], hk, accA);                                  \
                accN = fmaf(wN[k], hk, accN);                                  \
            }
            KSTEP(0)  KSTEP(1)  KSTEP(2)  KSTEP(3)  KSTEP(4)  KSTEP(5)
            KSTEP(6)  KSTEP(7)  KSTEP(8)  KSTEP(9)  KSTEP(10) KSTEP(11)
            KSTEP(12) KSTEP(13) KSTEP(14) KSTEP(15) KSTEP(16) KSTEP(17)
            KSTEP(18) KSTEP(19) KSTEP(20) KSTEP(21) KSTEP(22)
#undef KSTEP

            float xA = __half2float(hA[s]);  // xr (lower) / xz (upper)
            float xN = __half2float(hN[s]);  // xn (both halves)

            // one sigmoid pass activates r (lower half) AND z (upper half)
            float rz = sigm(xA + accA);

            // lower half: r is lane-local; pull z from the matching upper lane.
            // (shuffle latency overlaps the tanh below)
            float r = rz;
            float z = __shfl(rz, 32 + j, 64);

            float n = tanh_f(fmaf(r, accN, xN));
            h = fmaf(z, h - n, n);           // (1-z)*n + z*h
            if (act) ap[s * H_] = fmaf(pwj, h, pbj);
        }
        cA = nxA;
        cN = nxN;
    }
    if (act) out[(size_t)B_ * T_ * H_ + (size_t)b * H_ + jj] = h;
}

extern "C" void kernel_launch(void* const* d_in, const int* in_sizes, int n_in,
                              void* d_out, int out_size, void* d_ws, size_t ws_size,
                              hipStream_t stream) {
    const float* task = (const float*)d_in[0];  // (B, T, I)
    const float* Wih  = (const float*)d_in[1];  // (3H, I)
    const float* Whh  = (const float*)d_in[2];  // (3H, H)
    const float* bih  = (const float*)d_in[3];  // (3H,)
    const float* bhh  = (const float*)d_in[4];  // (3H,)
    const float* pw   = (const float*)d_in[5];  // (H,)
    const float* pb   = (const float*)d_in[6];  // (H,)
    float* out = (float*)d_out;                 // action_pred (B,T,H) ++ hidden (1,B,H)
    __half* xgbuf = (__half*)d_ws;              // transposed (B, G_, T) fp16 = 144.7 MB

    k_xproj<<<B_ * 4, TT_, 0, stream>>>(task, Wih, bih, xgbuf);
    k_scan<<<B_, 64, 0, stream>>>(xgbuf, Whh, bhh, pw, pb, out);
}